// Round 4
// baseline (394.412 us; speedup 1.0000x reference)
//
#include <hip/hip_runtime.h>

// Problem constants (from reference setup_inputs)
#define BB 2
#define NN 4096
#define DD 512
#define EE 16
#define HH 2048
#define CAP 1024            // capacity = int((4096*2)*2.0/16) = 1024
#define NTOK (BB*NN)        // 8192
#define MM (BB*CAP)         // 2048 = per-expert logical M
#define MAXSTRIP 160        // >= worst-case active 128-row strips (<=158)

typedef unsigned short ushort_t;
typedef __attribute__((ext_vector_type(8))) short bf16x8;   // 8 bf16 = 4 VGPRs
typedef __attribute__((ext_vector_type(4))) float floatx4;  // MFMA accumulator

// round-to-nearest-even f32 -> bf16 bit pattern
__device__ __forceinline__ ushort_t f2bf(float f) {
    union { float f; unsigned u; } v; v.f = f;
    unsigned r = v.u + 0x7fffu + ((v.u >> 16) & 1u);
    return (ushort_t)(r >> 16);
}

// async global->LDS, 16B per lane (global_load_lds_dwordx4).
__device__ __forceinline__ void cp16(const void* g, void* l) {
    __builtin_amdgcn_global_load_lds(
        (const __attribute__((address_space(1))) void*)g,
        (__attribute__((address_space(3))) void*)l, 16, 0, 0);
}

// ---------------------------------------------------------------------------
// Kernel 1: gating (f32-exact selection) + fused bf16 conversion of x.
// One wave per token; lane owns 8 consecutive d. Writes e1,e2,g1,g2,xbf.
// ---------------------------------------------------------------------------
__launch_bounds__(256)
__global__ void gating_kernel(const float* __restrict__ x,
                              const float* __restrict__ wg,
                              int* __restrict__ e1, int* __restrict__ e2,
                              float* __restrict__ g1, float* __restrict__ g2,
                              ushort_t* __restrict__ xbf) {
    int wave = threadIdx.x >> 6;
    int lane = threadIdx.x & 63;
    int t = blockIdx.x * 4 + wave;
    const float* xp = x + (size_t)t * DD;

    float4 xa = ((const float4*)xp)[lane * 2];
    float4 xb = ((const float4*)xp)[lane * 2 + 1];
    float xs[8] = {xa.x, xa.y, xa.z, xa.w, xb.x, xb.y, xb.z, xb.w};

    ushort4 h0, h1;
    h0.x = f2bf(xs[0]); h0.y = f2bf(xs[1]); h0.z = f2bf(xs[2]); h0.w = f2bf(xs[3]);
    h1.x = f2bf(xs[4]); h1.y = f2bf(xs[5]); h1.z = f2bf(xs[6]); h1.w = f2bf(xs[7]);
    ushort4* xo = (ushort4*)(xbf + (size_t)t * DD);
    xo[lane * 2] = h0; xo[lane * 2 + 1] = h1;

    float acc[EE];
#pragma unroll
    for (int e = 0; e < EE; e++) acc[e] = 0.f;
    int d0 = lane * 8;
#pragma unroll
    for (int j = 0; j < 8; j++) {
        const float* wrow = wg + (d0 + j) * EE;
#pragma unroll
        for (int e = 0; e < EE; e++) acc[e] = fmaf(xs[j], wrow[e], acc[e]);
    }
#pragma unroll
    for (int off = 32; off > 0; off >>= 1) {
#pragma unroll
        for (int e = 0; e < EE; e++) acc[e] += __shfl_xor(acc[e], off, 64);
    }
    if (lane == 0) {
        float m = acc[0];
#pragma unroll
        for (int e = 1; e < EE; e++) m = fmaxf(m, acc[e]);
        float p[EE]; float s = 0.f;
#pragma unroll
        for (int e = 0; e < EE; e++) { p[e] = __expf(acc[e] - m); s += p[e]; }
        float inv = 1.f / s;
#pragma unroll
        for (int e = 0; e < EE; e++) p[e] *= inv;
        int i1 = 0; float v1 = p[0];
#pragma unroll
        for (int e = 1; e < EE; e++) if (p[e] > v1) { v1 = p[e]; i1 = e; }
        int i2 = (i1 == 0) ? 1 : 0; float v2 = p[i2];
#pragma unroll
        for (int e = 0; e < EE; e++)
            if (e != i1 && p[e] > v2) { v2 = p[e]; i2 = e; }
        float denom = v1 + v2 + 1e-9f;
        e1[t] = i1; e2[t] = i2;
        g1[t] = v1 / denom; g2[t] = v2 / denom;
    }
}

// ---------------------------------------------------------------------------
// Kernel 2: per-(b,e) exclusive scan over token order -> slot assignment with
// capacity drop. Writes s2t (token or -1 for ALL CAP slots), s2g, used[e][b].
// ---------------------------------------------------------------------------
__launch_bounds__(256)
__global__ void scan_kernel(const int* __restrict__ e1, const int* __restrict__ e2,
                            const float* __restrict__ g1, const float* __restrict__ g2,
                            int* __restrict__ s2t, float* __restrict__ s2g,
                            int* __restrict__ used) {
    int b = blockIdx.x / EE;
    int e = blockIdx.x % EE;
    int tid = threadIdx.x;
    const int base = b * NN;
    int n0 = tid * 16;

    unsigned m1 = 0, m2 = 0;
    int c1 = 0, c2 = 0;
#pragma unroll
    for (int j = 0; j < 16; j++) {
        int n = n0 + j;
        if (e1[base + n] == e) { m1 |= 1u << j; c1++; }
        if (e2[base + n] == e) { m2 |= 1u << j; c2++; }
    }
    __shared__ int s1[256], s2[256];
    __shared__ int s_used;
    s1[tid] = c1; s2[tid] = c2;
    __syncthreads();
    for (int off = 1; off < 256; off <<= 1) {
        int a1 = (tid >= off) ? s1[tid - off] : 0;
        int a2 = (tid >= off) ? s2[tid - off] : 0;
        __syncthreads();
        s1[tid] += a1; s2[tid] += a2;
        __syncthreads();
    }
    int total1 = s1[255];
    int total2 = s2[255];
    int kept1 = min(total1, CAP);
    int ex1 = s1[tid] - c1;
    int ex2 = s2[tid] - c2 + kept1;
    const int sbase = (e * BB + b) * CAP;
#pragma unroll
    for (int j = 0; j < 16; j++) {
        int n = n0 + j;
        if (m1 & (1u << j)) {
            if (ex1 < CAP) { s2t[sbase + ex1] = base + n; s2g[sbase + ex1] = g1[base + n]; }
            ex1++;
        }
        if (m2 & (1u << j)) {
            if (ex2 < CAP) { s2t[sbase + ex2] = base + n; s2g[sbase + ex2] = g2[base + n]; }
            ex2++;
        }
    }
    if (tid == 255) {
        int kept2 = min(total2, max(0, CAP - kept1));
        int u = kept1 + kept2;
        used[e * BB + b] = u;
        s_used = u;
    }
    __syncthreads();
    for (int i = s_used + tid; i < CAP; i += 256) s2t[sbase + i] = -1;
}

// ---------------------------------------------------------------------------
// Kernel 3: build the active-strip worklist. Entry = (e<<16)|ytile; strip id
// (= compact hid row block) is the entry's position. wl[MAXSTRIP] = count.
// ---------------------------------------------------------------------------
__global__ void worklist_kernel(const int* __restrict__ used, int* __restrict__ wl) {
    __shared__ int ns[32], pre[32];
    int i = threadIdx.x;
    if (i < 32) {
        int e = i >> 1, b = i & 1;
        ns[i] = (used[e * BB + b] + 127) >> 7;
    }
    __syncthreads();
    if (i == 0) {
        int acc = 0;
        for (int j = 0; j < 32; j++) { pre[j] = acc; acc += ns[j]; }
        wl[MAXSTRIP] = acc;
    }
    __syncthreads();
    if (i < 32) {
        int e = i >> 1, b = i & 1;
        int p = pre[i];
        for (int s = 0; s < ns[i]; s++)
            wl[p + s] = (e << 16) | (b * 8 + s);
    }
}

// ---------------------------------------------------------------------------
// Kernel 4: per-expert transpose + bf16: in f32 [E][R][C] -> out bf16 [E][C][R].
// ---------------------------------------------------------------------------
__global__ void transpose_bf16(const float* __restrict__ in,
                               ushort_t* __restrict__ outp, int R, int C) {
    __shared__ float tile[32][33];
    const float* slab = in + (size_t)blockIdx.z * R * C;
    ushort_t* oslab = outp + (size_t)blockIdx.z * R * C;
    int c0 = blockIdx.x * 32, r0 = blockIdx.y * 32;
    int tx = threadIdx.x, ty = threadIdx.y;   // (32, 8)
#pragma unroll
    for (int j = 0; j < 4; j++)
        tile[ty + j * 8][tx] = slab[(size_t)(r0 + ty + j * 8) * C + c0 + tx];
    __syncthreads();
#pragma unroll
    for (int j = 0; j < 4; j++)
        oslab[(size_t)(c0 + ty + j * 8) * R + r0 + tx] = f2bf(tile[tx][ty + j * 8]);
}

// ---------------------------------------------------------------------------
// Kernel 5: bf16 MFMA GEMM over worklist strips, software-pipelined K-loop:
// double-buffered LDS, raw s_barrier + fine s_waitcnt vmcnt(N) — prefetch of
// tile k+1 stays in flight across the barrier (no __syncthreads / vmcnt(0)
// drain in the loop). XOR-swizzled staging (global side) -> 0 bank conflicts.
//   MODE 0 (GEMM1): 128x128 tile, K=512. A rows gathered from xbf via s2t
//                   (invalid rows load token 0, masked at epilogue);
//                   writes relu -> hid[strip] bf16.
//   MODE 1 (GEMM2): 128x64 tile, K=2048, A = hid[strip], B = w2t;
//                   epilogue scatters gate*acc into out via atomicAdd.
// ---------------------------------------------------------------------------
template <int MODE>
__launch_bounds__(256)
__global__ void gemm_mfma(const ushort_t* __restrict__ Abase,
                          const ushort_t* __restrict__ Bt,
                          void* __restrict__ Cout,
                          const int* __restrict__ wl,
                          const int* __restrict__ s2t,
                          const float* __restrict__ s2g) {
    constexpr int TN = (MODE == 0) ? 128 : 64;   // tile N
    constexpr int K  = (MODE == 0) ? DD : HH;    // GEMM K
    constexpr int KITERS = K / 32;
    constexpr int NV = (MODE == 0) ? 4 : 3;      // cp16 per thread per k-iter
    constexpr int MT = (MODE == 0) ? 4 : 2;      // m-tiles per wave

    int wi = blockIdx.y;
    if (wi >= wl[MAXSTRIP]) return;
    int entry = wl[wi];
    int e = entry >> 16;
    int ytile = entry & 0xffff;
    int col0 = blockIdx.x * TN;

    __shared__ ushort_t As[2][128 * 32];
    __shared__ ushort_t Bs[2][TN * 32];

    int tid = threadIdx.x;
    int lane = tid & 63;
    int wid = tid >> 6;
    int wave_m = (MODE == 0) ? ((wid & 1) << 6) : (wid << 5);
    int wave_n = (MODE == 0) ? ((wid >> 1) << 6) : 0;
    int lm = lane & 15;
    int quad = lane >> 4;
    // fragment-read swizzle: global chunk (r, c) stored at LDS col c ^ ((r>>1)&3)
    int sw = (quad ^ ((lm >> 1) & 3)) * 8;

    // per-thread global chunk base pointers (k = 0)
    const ushort_t* ga[2];
    const ushort_t* gb[NV - 2];
#pragma unroll
    for (int it = 0; it < 2; it++) {
        int idx = it * 256 + tid;
        int r = idx >> 2;
        int cg = (idx & 3) ^ ((r >> 1) & 3);
        if (MODE == 0) {
            int tok = s2t[e * MM + ytile * 128 + r];
            if (tok < 0) tok = 0;   // dummy valid row; result masked at epilogue
            ga[it] = Abase + (size_t)tok * DD + cg * 8;
        } else {
            ga[it] = Abase + (size_t)(wi * 128 + r) * HH + cg * 8;
        }
    }
#pragma unroll
    for (int it = 0; it < NV - 2; it++) {
        int idx = it * 256 + tid;
        int r = idx >> 2;
        int cg = (idx & 3) ^ ((r >> 1) & 3);
        gb[it] = Bt + (size_t)e * HH * DD + (size_t)(col0 + r) * K + cg * 8;
    }

    auto stage = [&](int buf, int ki) {
#pragma unroll
        for (int it = 0; it < 2; it++)
            cp16(ga[it] + ki * 32, &As[buf][(it * 256 + tid) * 8]);
#pragma unroll
        for (int it = 0; it < NV - 2; it++)
            cp16(gb[it] + ki * 32, &Bs[buf][(it * 256 + tid) * 8]);
    };

    floatx4 acc[MT][4];
#pragma unroll
    for (int i = 0; i < MT; i++)
#pragma unroll
        for (int j = 0; j < 4; j++)
            acc[i][j] = (floatx4)(0.f);

    stage(0, 0);
#pragma unroll 2
    for (int ki = 0; ki < KITERS; ki++) {
        int cur = ki & 1;
        if (ki + 1 < KITERS) {
            stage(cur ^ 1, ki + 1);   // prefetch next tile, stays in flight
            asm volatile("s_waitcnt vmcnt(%0)\ns_barrier" :: "i"(NV) : "memory");
        } else {
            asm volatile("s_waitcnt vmcnt(0)\ns_barrier" ::: "memory");
        }
        bf16x8 af[MT], bfr[4];
#pragma unroll
        for (int mt = 0; mt < MT; mt++)
            af[mt] = *(const bf16x8*)&As[cur][(wave_m + mt * 16 + lm) * 32 + sw];
#pragma unroll
        for (int nt = 0; nt < 4; nt++)
            bfr[nt] = *(const bf16x8*)&Bs[cur][(wave_n + nt * 16 + lm) * 32 + sw];
#pragma unroll
        for (int mt = 0; mt < MT; mt++)
#pragma unroll
            for (int nt = 0; nt < 4; nt++)
                acc[mt][nt] = __builtin_amdgcn_mfma_f32_16x16x32_bf16(
                    af[mt], bfr[nt], acc[mt][nt], 0, 0, 0);
        // all waves done reading buf[cur] before anyone overwrites it
        asm volatile("s_waitcnt lgkmcnt(0)\ns_barrier" ::: "memory");
    }

    // C/D layout: col = lane&15, row = (lane>>4)*4 + reg  [m89/m91-verified]
    if (MODE == 0) {
        ushort_t* hp = (ushort_t*)Cout + (size_t)wi * 128 * HH;
#pragma unroll
        for (int mt = 0; mt < MT; mt++) {
#pragma unroll
            for (int r = 0; r < 4; r++) {
                int row = wave_m + mt * 16 + quad * 4 + r;
#pragma unroll
                for (int nt = 0; nt < 4; nt++) {
                    int col = col0 + wave_n + nt * 16 + lm;
                    hp[(size_t)row * HH + col] = f2bf(fmaxf(acc[mt][nt][r], 0.f));
                }
            }
        }
    } else {
        float* outp = (float*)Cout;
#pragma unroll
        for (int mt = 0; mt < MT; mt++) {
#pragma unroll
            for (int r = 0; r < 4; r++) {
                int row = wave_m + mt * 16 + quad * 4 + r;
                int slot = e * MM + ytile * 128 + row;
                int tok = s2t[slot];
                if (tok < 0) continue;
                float g = s2g[slot];
#pragma unroll
                for (int nt = 0; nt < 4; nt++) {
                    int col = col0 + wave_n + nt * 16 + lm;
                    atomicAdd(outp + (size_t)tok * DD + col, g * acc[mt][nt][r]);
                }
            }
        }
    }
}

// ---------------------------------------------------------------------------
// Workspace layout (bytes), total ~126.2 MB (< 151.2 MB proven):
//   0         e1 32768 | 32768 e2 | 65536 g1 | 98304 g2
//   131072    used (pad 1024)
//   132096    wl   (161 ints, pad 1024)
//   133120    s2t  131072
//   264192    s2g  131072
//   395264    xbf  bf16 [8192][512]            =  8,388,608
//   8783872   wt   bf16 (w1t, then w2t)        = 33,554,432
//   42338304  hid  bf16 [160 strips][128][2048]= 83,886,080
// ---------------------------------------------------------------------------
extern "C" void kernel_launch(void* const* d_in, const int* in_sizes, int n_in,
                              void* d_out, int out_size, void* d_ws, size_t ws_size,
                              hipStream_t stream) {
    const float* x  = (const float*)d_in[0];
    const float* wg = (const float*)d_in[1];
    const float* w1 = (const float*)d_in[2];
    const float* w2 = (const float*)d_in[3];
    float* out = (float*)d_out;

    char* ws = (char*)d_ws;
    int*      e1   = (int*)(ws);
    int*      e2   = (int*)(ws + 32768);
    float*    g1   = (float*)(ws + 65536);
    float*    g2   = (float*)(ws + 98304);
    int*      used = (int*)(ws + 131072);
    int*      wl   = (int*)(ws + 132096);
    int*      s2t  = (int*)(ws + 133120);
    float*    s2g  = (float*)(ws + 264192);
    ushort_t* xbf  = (ushort_t*)(ws + 395264);
    ushort_t* wt   = (ushort_t*)(ws + 8783872);
    ushort_t* hid  = (ushort_t*)(ws + 42338304);

    hipMemsetAsync(out, 0, (size_t)NTOK * DD * sizeof(float), stream);

    gating_kernel<<<NTOK / 4, 256, 0, stream>>>(x, wg, e1, e2, g1, g2, xbf);
    scan_kernel<<<BB * EE, 256, 0, stream>>>(e1, e2, g1, g2, s2t, s2g, used);
    worklist_kernel<<<1, 64, 0, stream>>>(used, wl);

    // GEMM1: gather(xbf) @ w1t -> relu -> hid (compact strips)
    transpose_bf16<<<dim3(HH / 32, DD / 32, EE), dim3(32, 8), 0, stream>>>(w1, wt, DD, HH);
    gemm_mfma<0><<<dim3(HH / 128, MAXSTRIP), 256, 0, stream>>>(xbf, wt, hid, wl, s2t, s2g);

    // GEMM2: hid @ w2t -> gate-weighted scatter-add into out (full K = 2048)
    transpose_bf16<<<dim3(DD / 32, HH / 32, EE), dim3(32, 8), 0, stream>>>(w2, wt, HH, DD);
    gemm_mfma<1><<<dim3(DD / 64, MAXSTRIP), 256, 0, stream>>>(hid, wt, out, wl, s2t, s2g);
}

// Round 5
// 366.608 us; speedup vs baseline: 1.0758x; 1.0758x over previous
//
#include <hip/hip_runtime.h>

// Problem constants (from reference setup_inputs)
#define BB 2
#define NN 4096
#define DD 512
#define EE 16
#define HH 2048
#define CAP 1024            // capacity = int((4096*2)*2.0/16) = 1024
#define NTOK (BB*NN)        // 8192
#define MM (BB*CAP)         // 2048 = per-expert logical M
#define MAXSTRIP 160        // worst-case total 128-row strips (<=158)

typedef unsigned short ushort_t;
typedef __attribute__((ext_vector_type(8))) short bf16x8;   // 8 bf16 = 4 VGPRs
typedef __attribute__((ext_vector_type(4))) float floatx4;  // MFMA accumulator

// round-to-nearest-even f32 -> bf16 bit pattern
__device__ __forceinline__ ushort_t f2bf(float f) {
    union { float f; unsigned u; } v; v.f = f;
    unsigned r = v.u + 0x7fffu + ((v.u >> 16) & 1u);
    return (ushort_t)(r >> 16);
}

// async global->LDS, 16B per lane (global_load_lds_dwordx4).
__device__ __forceinline__ void cp16(const void* g, void* l) {
    __builtin_amdgcn_global_load_lds(
        (const __attribute__((address_space(1))) void*)g,
        (__attribute__((address_space(3))) void*)l, 16, 0, 0);
}

// ---------------------------------------------------------------------------
// Kernel 1: gating (f32-exact selection) + fused bf16 conversion of x.
// ---------------------------------------------------------------------------
__launch_bounds__(256)
__global__ void gating_kernel(const float* __restrict__ x,
                              const float* __restrict__ wg,
                              int* __restrict__ e1, int* __restrict__ e2,
                              float* __restrict__ g1, float* __restrict__ g2,
                              ushort_t* __restrict__ xbf) {
    int wave = threadIdx.x >> 6;
    int lane = threadIdx.x & 63;
    int t = blockIdx.x * 4 + wave;
    const float* xp = x + (size_t)t * DD;

    float4 xa = ((const float4*)xp)[lane * 2];
    float4 xb = ((const float4*)xp)[lane * 2 + 1];
    float xs[8] = {xa.x, xa.y, xa.z, xa.w, xb.x, xb.y, xb.z, xb.w};

    ushort4 h0, h1;
    h0.x = f2bf(xs[0]); h0.y = f2bf(xs[1]); h0.z = f2bf(xs[2]); h0.w = f2bf(xs[3]);
    h1.x = f2bf(xs[4]); h1.y = f2bf(xs[5]); h1.z = f2bf(xs[6]); h1.w = f2bf(xs[7]);
    ushort4* xo = (ushort4*)(xbf + (size_t)t * DD);
    xo[lane * 2] = h0; xo[lane * 2 + 1] = h1;

    float acc[EE];
#pragma unroll
    for (int e = 0; e < EE; e++) acc[e] = 0.f;
    int d0 = lane * 8;
#pragma unroll
    for (int j = 0; j < 8; j++) {
        const float* wrow = wg + (d0 + j) * EE;
#pragma unroll
        for (int e = 0; e < EE; e++) acc[e] = fmaf(xs[j], wrow[e], acc[e]);
    }
#pragma unroll
    for (int off = 32; off > 0; off >>= 1) {
#pragma unroll
        for (int e = 0; e < EE; e++) acc[e] += __shfl_xor(acc[e], off, 64);
    }
    if (lane == 0) {
        float m = acc[0];
#pragma unroll
        for (int e = 1; e < EE; e++) m = fmaxf(m, acc[e]);
        float p[EE]; float s = 0.f;
#pragma unroll
        for (int e = 0; e < EE; e++) { p[e] = __expf(acc[e] - m); s += p[e]; }
        float inv = 1.f / s;
#pragma unroll
        for (int e = 0; e < EE; e++) p[e] *= inv;
        int i1 = 0; float v1 = p[0];
#pragma unroll
        for (int e = 1; e < EE; e++) if (p[e] > v1) { v1 = p[e]; i1 = e; }
        int i2 = (i1 == 0) ? 1 : 0; float v2 = p[i2];
#pragma unroll
        for (int e = 0; e < EE; e++)
            if (e != i1 && p[e] > v2) { v2 = p[e]; i2 = e; }
        float denom = v1 + v2 + 1e-9f;
        e1[t] = i1; e2[t] = i2;
        g1[t] = v1 / denom; g2[t] = v2 / denom;
    }
}

// ---------------------------------------------------------------------------
// Kernel 2: per-(b,e) exclusive scan -> slot assignment with capacity drop.
// Writes s2t (token or -1 for ALL CAP slots), s2g, used[e][b].
// ---------------------------------------------------------------------------
__launch_bounds__(256)
__global__ void scan_kernel(const int* __restrict__ e1, const int* __restrict__ e2,
                            const float* __restrict__ g1, const float* __restrict__ g2,
                            int* __restrict__ s2t, float* __restrict__ s2g,
                            int* __restrict__ used) {
    int b = blockIdx.x / EE;
    int e = blockIdx.x % EE;
    int tid = threadIdx.x;
    const int base = b * NN;
    int n0 = tid * 16;

    unsigned m1 = 0, m2 = 0;
    int c1 = 0, c2 = 0;
#pragma unroll
    for (int j = 0; j < 16; j++) {
        int n = n0 + j;
        if (e1[base + n] == e) { m1 |= 1u << j; c1++; }
        if (e2[base + n] == e) { m2 |= 1u << j; c2++; }
    }
    __shared__ int s1[256], s2[256];
    __shared__ int s_used;
    s1[tid] = c1; s2[tid] = c2;
    __syncthreads();
    for (int off = 1; off < 256; off <<= 1) {
        int a1 = (tid >= off) ? s1[tid - off] : 0;
        int a2 = (tid >= off) ? s2[tid - off] : 0;
        __syncthreads();
        s1[tid] += a1; s2[tid] += a2;
        __syncthreads();
    }
    int total1 = s1[255];
    int total2 = s2[255];
    int kept1 = min(total1, CAP);
    int ex1 = s1[tid] - c1;
    int ex2 = s2[tid] - c2 + kept1;
    const int sbase = (e * BB + b) * CAP;
#pragma unroll
    for (int j = 0; j < 16; j++) {
        int n = n0 + j;
        if (m1 & (1u << j)) {
            if (ex1 < CAP) { s2t[sbase + ex1] = base + n; s2g[sbase + ex1] = g1[base + n]; }
            ex1++;
        }
        if (m2 & (1u << j)) {
            if (ex2 < CAP) { s2t[sbase + ex2] = base + n; s2g[sbase + ex2] = g2[base + n]; }
            ex2++;
        }
    }
    if (tid == 255) {
        int kept2 = min(total2, max(0, CAP - kept1));
        int u = kept1 + kept2;
        used[e * BB + b] = u;
        s_used = u;
    }
    __syncthreads();
    for (int i = s_used + tid; i < CAP; i += 256) s2t[sbase + i] = -1;
}

// ---------------------------------------------------------------------------
// Kernel 3: build XCD-pinned job schedules. Expert e is pinned to XCD e&7
// (two experts per XCD). With grid (8, slots), linear block id = x + 8*y, and
// round-robin dispatch puts all blocks with blockIdx.x == x on XCD x, so each
// XCD's L2 only holds its 2 experts' weight slabs + A rows.
// meta layout (ints): [0..7] count1/xcd, [8..15] count2/xcd,
//                     [16..4111] sched1 (8 x 512), [4112..5135] sched2 (8 x 128)
// job = (e<<17) | (wi<<9) | (ytile<<5) | col   (wi = global compact strip id)
// ---------------------------------------------------------------------------
__global__ void schedule_kernel(const int* __restrict__ used, int* __restrict__ meta) {
    __shared__ int ns[32], pre[32];
    int i = threadIdx.x;
    if (i < 32) {
        int e = i >> 1, b = i & 1;
        ns[i] = (used[e * BB + b] + 127) >> 7;
    }
    __syncthreads();
    if (i == 0) {
        int acc = 0;
        for (int j = 0; j < 32; j++) { pre[j] = acc; acc += ns[j]; }
    }
    __syncthreads();
    if (i < 16) {
        int e = i;
        int xcd = e & 7;
        int mine  = ns[2 * e] + ns[2 * e + 1];
        int po    = (e < 8) ? (e + 8) : (e - 8);
        int other = ns[2 * po] + ns[2 * po + 1];
        if (e < 8) {
            meta[xcd]     = (mine + other) * 16;   // GEMM1 jobs on this XCD
            meta[8 + xcd] = (mine + other) * 4;    // GEMM2 jobs on this XCD
        }
        int off = (e < 8) ? 0 : other;             // partner's jobs come first
        int* sc1 = meta + 16 + xcd * 512 + off * 16;
        int j = 0;
        for (int col = 0; col < 16; col++)
            for (int bb = 0; bb < 2; bb++)
                for (int s = 0; s < ns[2 * e + bb]; s++) {
                    int wi = pre[2 * e + bb] + s;
                    sc1[j++] = (e << 17) | (wi << 9) | ((bb * 8 + s) << 5) | col;
                }
        int* sc2 = meta + 16 + 4096 + xcd * 128 + off * 4;
        j = 0;
        for (int col = 0; col < 4; col++)
            for (int bb = 0; bb < 2; bb++)
                for (int s = 0; s < ns[2 * e + bb]; s++) {
                    int wi = pre[2 * e + bb] + s;
                    sc2[j++] = (e << 17) | (wi << 9) | ((bb * 8 + s) << 5) | col;
                }
    }
}

// ---------------------------------------------------------------------------
// Kernel 4: per-expert transpose + bf16: in f32 [E][R][C] -> out bf16 [E][C][R].
// ---------------------------------------------------------------------------
__global__ void transpose_bf16(const float* __restrict__ in,
                               ushort_t* __restrict__ outp, int R, int C) {
    __shared__ float tile[32][33];
    const float* slab = in + (size_t)blockIdx.z * R * C;
    ushort_t* oslab = outp + (size_t)blockIdx.z * R * C;
    int c0 = blockIdx.x * 32, r0 = blockIdx.y * 32;
    int tx = threadIdx.x, ty = threadIdx.y;   // (32, 8)
#pragma unroll
    for (int j = 0; j < 4; j++)
        tile[ty + j * 8][tx] = slab[(size_t)(r0 + ty + j * 8) * C + c0 + tx];
    __syncthreads();
#pragma unroll
    for (int j = 0; j < 4; j++)
        oslab[(size_t)(c0 + ty + j * 8) * R + r0 + tx] = f2bf(tile[tx][ty + j * 8]);
}

// ---------------------------------------------------------------------------
// Kernel 5: bf16 MFMA GEMM, 128x128 tile, BK=32, XCD-pinned job schedule,
// software-pipelined dbuf K-loop (fine vmcnt + raw s_barrier), XOR-swizzled
// staging (0 bank conflicts).
//   MODE 0 (GEMM1): K=512,  A gathered from xbf via s2t, relu -> hid[strip].
//   MODE 1 (GEMM2): K=2048, A = hid[strip], epilogue gate*acc atomicAdd -> out.
// ---------------------------------------------------------------------------
template <int MODE>
__launch_bounds__(256)
__global__ void gemm_mfma(const ushort_t* __restrict__ Abase,
                          const ushort_t* __restrict__ Bt,
                          void* __restrict__ Cout,
                          const int* __restrict__ meta,
                          const int* __restrict__ s2t,
                          const float* __restrict__ s2g) {
    constexpr int K = (MODE == 0) ? DD : HH;
    constexpr int KITERS = K / 32;

    int xcd = blockIdx.x;
    if ((int)blockIdx.y >= meta[(MODE == 0 ? 0 : 8) + xcd]) return;
    int job = meta[16 + (MODE == 0 ? 0 : 4096) + xcd * (MODE == 0 ? 512 : 128) + blockIdx.y];
    int col0  = (job & 31) * 128;
    int ytile = (job >> 5) & 15;
    int wi    = (job >> 9) & 255;
    int e     = job >> 17;

    __shared__ ushort_t As[2][128 * 32];
    __shared__ ushort_t Bs[2][128 * 32];

    int tid = threadIdx.x;
    int lane = tid & 63;
    int wid = tid >> 6;
    int wave_m = (wid & 1) << 6;
    int wave_n = (wid >> 1) << 6;
    int lm = lane & 15;
    int quad = lane >> 4;
    // fragment-read swizzle: global chunk (r, c) stored at LDS col c ^ ((r>>1)&3)
    int sw = (quad ^ ((lm >> 1) & 3)) * 8;

    // per-thread global chunk base pointers (k = 0)
    const ushort_t* ga[2];
    const ushort_t* gb[2];
#pragma unroll
    for (int it = 0; it < 2; it++) {
        int idx = it * 256 + tid;
        int r = idx >> 2;
        int cg = (idx & 3) ^ ((r >> 1) & 3);
        if (MODE == 0) {
            int tok = s2t[e * MM + ytile * 128 + r];
            if (tok < 0) tok = 0;   // dummy valid row; masked at epilogue
            ga[it] = Abase + (size_t)tok * DD + cg * 8;
        } else {
            ga[it] = Abase + (size_t)(wi * 128 + r) * HH + cg * 8;
        }
        gb[it] = Bt + (size_t)e * HH * DD + (size_t)(col0 + r) * K + cg * 8;
    }

    auto stage = [&](int buf, int ki) {
#pragma unroll
        for (int it = 0; it < 2; it++)
            cp16(ga[it] + ki * 32, &As[buf][(it * 256 + tid) * 8]);
#pragma unroll
        for (int it = 0; it < 2; it++)
            cp16(gb[it] + ki * 32, &Bs[buf][(it * 256 + tid) * 8]);
    };

    floatx4 acc[4][4];
#pragma unroll
    for (int i = 0; i < 4; i++)
#pragma unroll
        for (int j = 0; j < 4; j++)
            acc[i][j] = (floatx4)(0.f);

    stage(0, 0);
#pragma unroll 2
    for (int ki = 0; ki < KITERS; ki++) {
        int cur = ki & 1;
        if (ki + 1 < KITERS) {
            stage(cur ^ 1, ki + 1);   // prefetch next tile, stays in flight
            asm volatile("s_waitcnt vmcnt(4)\ns_barrier" ::: "memory");
        } else {
            asm volatile("s_waitcnt vmcnt(0)\ns_barrier" ::: "memory");
        }
        bf16x8 af[4], bfr[4];
#pragma unroll
        for (int mt = 0; mt < 4; mt++)
            af[mt] = *(const bf16x8*)&As[cur][(wave_m + mt * 16 + lm) * 32 + sw];
#pragma unroll
        for (int nt = 0; nt < 4; nt++)
            bfr[nt] = *(const bf16x8*)&Bs[cur][(wave_n + nt * 16 + lm) * 32 + sw];
#pragma unroll
        for (int mt = 0; mt < 4; mt++)
#pragma unroll
            for (int nt = 0; nt < 4; nt++)
                acc[mt][nt] = __builtin_amdgcn_mfma_f32_16x16x32_bf16(
                    af[mt], bfr[nt], acc[mt][nt], 0, 0, 0);
        // all waves done reading buf[cur] before anyone overwrites it
        asm volatile("s_waitcnt lgkmcnt(0)\ns_barrier" ::: "memory");
    }

    // C/D layout: col = lane&15, row = (lane>>4)*4 + reg  [m89/m91-verified]
    if (MODE == 0) {
        ushort_t* hp = (ushort_t*)Cout + (size_t)wi * 128 * HH;
#pragma unroll
        for (int mt = 0; mt < 4; mt++) {
#pragma unroll
            for (int r = 0; r < 4; r++) {
                int row = wave_m + mt * 16 + quad * 4 + r;
#pragma unroll
                for (int nt = 0; nt < 4; nt++) {
                    int col = col0 + wave_n + nt * 16 + lm;
                    hp[(size_t)row * HH + col] = f2bf(fmaxf(acc[mt][nt][r], 0.f));
                }
            }
        }
    } else {
        float* outp = (float*)Cout;
#pragma unroll
        for (int mt = 0; mt < 4; mt++) {
#pragma unroll
            for (int r = 0; r < 4; r++) {
                int row = wave_m + mt * 16 + quad * 4 + r;
                int slot = e * MM + ytile * 128 + row;
                int tok = s2t[slot];
                if (tok < 0) continue;
                float g = s2g[slot];
#pragma unroll
                for (int nt = 0; nt < 4; nt++) {
                    int col = col0 + wave_n + nt * 16 + lm;
                    atomicAdd(outp + (size_t)tok * DD + col, g * acc[mt][nt][r]);
                }
            }
        }
    }
}

// ---------------------------------------------------------------------------
// Workspace layout (bytes), total ~126.2 MB (< 151.2 MB proven):
//   0         e1 32768 | 32768 e2 | 65536 g1 | 98304 g2
//   131072    used (pad 1024)
//   132096    meta (5136 ints = 20544 B, pad to 20608)
//   152704    s2t  131072
//   283776    s2g  131072
//   414848    xbf  bf16 [8192][512]            =  8,388,608
//   8803456   wt   bf16 (w1t, then w2t)        = 33,554,432
//   42357888  hid  bf16 [160 strips][128][2048]= 83,886,080
// ---------------------------------------------------------------------------
extern "C" void kernel_launch(void* const* d_in, const int* in_sizes, int n_in,
                              void* d_out, int out_size, void* d_ws, size_t ws_size,
                              hipStream_t stream) {
    const float* x  = (const float*)d_in[0];
    const float* wg = (const float*)d_in[1];
    const float* w1 = (const float*)d_in[2];
    const float* w2 = (const float*)d_in[3];
    float* out = (float*)d_out;

    char* ws = (char*)d_ws;
    int*      e1   = (int*)(ws);
    int*      e2   = (int*)(ws + 32768);
    float*    g1   = (float*)(ws + 65536);
    float*    g2   = (float*)(ws + 98304);
    int*      used = (int*)(ws + 131072);
    int*      meta = (int*)(ws + 132096);
    int*      s2t  = (int*)(ws + 152704);
    float*    s2g  = (float*)(ws + 283776);
    ushort_t* xbf  = (ushort_t*)(ws + 414848);
    ushort_t* wt   = (ushort_t*)(ws + 8803456);
    ushort_t* hid  = (ushort_t*)(ws + 42357888);

    hipMemsetAsync(out, 0, (size_t)NTOK * DD * sizeof(float), stream);

    gating_kernel<<<NTOK / 4, 256, 0, stream>>>(x, wg, e1, e2, g1, g2, xbf);
    scan_kernel<<<BB * EE, 256, 0, stream>>>(e1, e2, g1, g2, s2t, s2g, used);
    schedule_kernel<<<1, 64, 0, stream>>>(used, meta);

    // GEMM1: gather(xbf) @ w1t -> relu -> hid (compact strips), XCD-pinned
    transpose_bf16<<<dim3(HH / 32, DD / 32, EE), dim3(32, 8), 0, stream>>>(w1, wt, DD, HH);
    gemm_mfma<0><<<dim3(8, 512), 256, 0, stream>>>(xbf, wt, hid, meta, s2t, s2g);

    // GEMM2: hid @ w2t -> gate-weighted scatter-add into out, XCD-pinned
    transpose_bf16<<<dim3(DD / 32, HH / 32, EE), dim3(32, 8), 0, stream>>>(w2, wt, HH, DD);
    gemm_mfma<1><<<dim3(8, 128), 256, 0, stream>>>(hid, wt, out, meta, s2t, s2g);
}